// Round 2
// baseline (2102.166 us; speedup 1.0000x reference)
//
#include <hip/hip_runtime.h>

// ---------------------------------------------------------------------------
// 2-layer GRU, H=256, seq=64, rows = B*N = 2048.
// Cooperative persistent kernel; phase t computes layer0(t) + layer1(t-1)
// -> 64 grid barriers. WG = (row-tile of 128) x (16 hidden dims).
// Weights pre-packed (bf16) to MFMA-B fragment layout, staged to LDS/phase.
// f32 h-state lives in registers (thread owns its (row,d) cells for all t);
// cross-WG h exchanged via bf16 rings in ws. Input/output dtype (f32 vs bf16)
// resolved at runtime by a device probe; all I/O branches on the flag.
// ---------------------------------------------------------------------------

typedef __attribute__((ext_vector_type(8))) __bf16 bf8;
typedef __attribute__((ext_vector_type(8))) unsigned short u16x8;
typedef __attribute__((ext_vector_type(4))) float f32x4;

#define MFMA16(A, B, C) __builtin_amdgcn_mfma_f32_16x16x32_bf16((A), (B), (C), 0, 0, 0)

#define ROWS 2048
#define HID 256
#define NW 768
#define SLOT (ROWS * HID)                       // 524288
#define OUT_HID_OFF ((size_t)64 * ROWS * HID)   // 33554432

static __device__ __forceinline__ float b2f(unsigned short u) {
  union { unsigned u32; float f; } v;
  v.u32 = ((unsigned)u) << 16;
  return v.f;
}
static __device__ __forceinline__ unsigned short f2b(float f) {
  unsigned u = __float_as_uint(f);
  u += 0x7fffu + ((u >> 16) & 1u);  // RNE
  return (unsigned short)(u >> 16);
}
static __device__ __forceinline__ float sigm(float x) {
  return 1.0f / (1.0f + __expf(-x));
}
static __device__ __forceinline__ float tanh_fast(float x) {
  x = fminf(15.0f, fmaxf(-15.0f, x));
  float e = __expf(2.0f * x);
  return (e - 1.0f) / (e + 1.0f);
}
static __device__ __forceinline__ float ldin(const void* p, int i, int f32w) {
  return f32w ? ((const float*)p)[i] : b2f(((const unsigned short*)p)[i]);
}
static __device__ __forceinline__ void stout(void* p, size_t i, float v, int f32w) {
  if (f32w) ((float*)p)[i] = v;
  else ((unsigned short*)p)[i] = f2b(v);
}

// --------------------------- dtype probe -----------------------------------
// Interpret first 256 u16 of x as bf16. In a real bf16 array all 256 are
// finite with |v| <= 8 (x ~ N(0,1)). In an f32 array, half are random
// mantissa halves -> wild exponents; count < 250 with overwhelming prob.
__global__ void probe_dtype(const unsigned short* x, unsigned* flag) {
  if (blockIdx.x != 0 || threadIdx.x != 0) return;
  int cnt = 0;
  for (int i = 0; i < 256; ++i) {
    float v = b2f(x[i]);
    if (v == v && fabsf(v) <= 8.0f) cnt++;
  }
  *flag = (cnt >= 250) ? 0u : 1u;  // 0 = bf16 world, 1 = f32 world
}

// --------------------------- weight pre-pack -------------------------------
// packed[nb][kk][lane][e] = W[kk*32 + (lane>>4)*8 + e][nb*16 + (lane&15)]
__global__ void pack_w(const void* __restrict__ W,
                       unsigned short* __restrict__ P, int KK,
                       const unsigned* __restrict__ flag) {
  int i = blockIdx.x * blockDim.x + threadIdx.x;
  int total = 48 * KK * 64;
  if (i >= total) return;
  int f32w = (int)*flag;
  int l = i & 63;
  int kk = (i >> 6) % KK;
  int nb = i / (64 * KK);
  int n = nb * 16 + (l & 15);
  int k0 = kk * 32 + (l >> 4) * 8;
  u16x8 tmp;
#pragma unroll
  for (int e = 0; e < 8; ++e) {
    float v = ldin(W, (k0 + e) * NW + n, f32w);
    tmp[e] = f2b(v);
  }
  *(u16x8*)(P + (size_t)i * 8) = tmp;
}

// --------------------------- grid barrier ----------------------------------
static __device__ __forceinline__ void gridbar(unsigned* cnt, unsigned target) {
  __syncthreads();  // drain all waves' stores (vmcnt 0) before arrive
  if (threadIdx.x == 0) {
    __threadfence();  // agent release: writeback L2 (cross-XCD visibility)
    __hip_atomic_fetch_add(cnt, 1u, __ATOMIC_RELEASE, __HIP_MEMORY_SCOPE_AGENT);
    unsigned v = __hip_atomic_load(cnt, __ATOMIC_RELAXED, __HIP_MEMORY_SCOPE_AGENT);
    while (v < target) {
      __builtin_amdgcn_s_sleep(1);
      v = __hip_atomic_load(cnt, __ATOMIC_RELAXED, __HIP_MEMORY_SCOPE_AGENT);
    }
    __threadfence();  // agent acquire: invalidate stale L2 lines
  }
  __syncthreads();
}

// --------------------------- GEMM pieces -----------------------------------
template <int KK>
static __device__ __forceinline__ void gemm_bf16A(
    const unsigned short* aBase, int rowStride,
    const unsigned short* smemBase, int lane,
    f32x4* aR, f32x4* aZ, f32x4* aT) {
#pragma unroll
  for (int kk = 0; kk < KK; ++kk) {
    bf8 A0 = *(const bf8*)(aBase + kk * 32);
    bf8 A1 = *(const bf8*)(aBase + 16 * rowStride + kk * 32);
    bf8 Br = *(const bf8*)(smemBase + (0 * KK + kk) * 512 + lane * 8);
    bf8 Bz = *(const bf8*)(smemBase + (1 * KK + kk) * 512 + lane * 8);
    bf8 Bn = *(const bf8*)(smemBase + (2 * KK + kk) * 512 + lane * 8);
    aR[0] = MFMA16(A0, Br, aR[0]);
    aR[1] = MFMA16(A1, Br, aR[1]);
    aZ[0] = MFMA16(A0, Bz, aZ[0]);
    aZ[1] = MFMA16(A1, Bz, aZ[1]);
    aT[0] = MFMA16(A0, Bn, aT[0]);
    aT[1] = MFMA16(A1, Bn, aT[1]);
  }
}

template <int KK>
static __device__ __forceinline__ void gemm_f32A(
    const float* aBase, int rowStride,
    const unsigned short* smemBase, int lane,
    f32x4* aR, f32x4* aZ, f32x4* aT) {
#pragma unroll
  for (int kk = 0; kk < KK; ++kk) {
    union { u16x8 u; bf8 b; } A0, A1;
#pragma unroll
    for (int e = 0; e < 8; ++e) {
      A0.u[e] = f2b(aBase[kk * 32 + e]);
      A1.u[e] = f2b(aBase[16 * rowStride + kk * 32 + e]);
    }
    bf8 Br = *(const bf8*)(smemBase + (0 * KK + kk) * 512 + lane * 8);
    bf8 Bz = *(const bf8*)(smemBase + (1 * KK + kk) * 512 + lane * 8);
    bf8 Bn = *(const bf8*)(smemBase + (2 * KK + kk) * 512 + lane * 8);
    aR[0] = MFMA16(A0.b, Br, aR[0]);
    aR[1] = MFMA16(A1.b, Br, aR[1]);
    aZ[0] = MFMA16(A0.b, Bz, aZ[0]);
    aZ[1] = MFMA16(A1.b, Bz, aZ[1]);
    aT[0] = MFMA16(A0.b, Bn, aT[0]);
    aT[1] = MFMA16(A1.b, Bn, aT[1]);
  }
}

// --------------------------- main kernel -----------------------------------
__global__ void __launch_bounds__(256, 1) gru_main(
    const void* __restrict__ x,
    const void* __restrict__ bi0, const void* __restrict__ bh0,
    const void* __restrict__ bi1, const void* __restrict__ bh1,
    const unsigned short* __restrict__ pwi0, const unsigned short* __restrict__ pwh0,
    const unsigned short* __restrict__ pwi1, const unsigned short* __restrict__ pwh1,
    void* __restrict__ out,
    unsigned short* __restrict__ h0b, unsigned short* __restrict__ h1b,
    unsigned* __restrict__ cnt, const unsigned* __restrict__ flag) {
  __shared__ __align__(16) unsigned short smem[24576];  // 48 KB

  const int f32w = (int)*flag;
  const int tid = threadIdx.x;
  const int lane = tid & 63;
  const int wid = tid >> 6;
  const int wg = blockIdx.x;
  const int rtile = wg & 15;   // 16 row tiles of 128
  const int slice = wg >> 4;   // 16 dim slices of 16

  const int d = slice * 16 + (lane & 15);
  const int rb = rtile * 128 + wid * 32;
  const int arow = rb + (lane & 15);
  const int koff = (lane >> 4) * 8;
  const int rl = (lane >> 4) * 4;

  const float iR0 = ldin(bi0, d, f32w) + ldin(bh0, d, f32w);
  const float iZ0 = ldin(bi0, 256 + d, f32w) + ldin(bh0, 256 + d, f32w);
  const float iI0 = ldin(bi0, 512 + d, f32w);
  const float iH0 = ldin(bh0, 512 + d, f32w);
  const float iR1 = ldin(bi1, d, f32w) + ldin(bh1, d, f32w);
  const float iZ1 = ldin(bi1, 256 + d, f32w) + ldin(bh1, 256 + d, f32w);
  const float iI1 = ldin(bi1, 512 + d, f32w);
  const float iH1 = ldin(bh1, 512 + d, f32w);

  // Register-resident f32 h-state: thread owns rows rb + f*16 + rl + j, col d.
  float h0p[2][4] = {{0, 0, 0, 0}, {0, 0, 0, 0}};
  float h1p[2][4] = {{0, 0, 0, 0}, {0, 0, 0, 0}};

  for (int t = 0; t <= 64; ++t) {
    const int sc = t & 1;
    const int sp = sc ^ 1;

    // ================= Layer 0, step t =================
    if (t < 64) {
      for (int i = tid; i < 384; i += 256) {  // wi0: 6 frags -> smem[0..3071]
        int g = i >> 7, r = i & 127;
        *(u16x8*)(smem + g * 1024 + r * 8) =
            *(const u16x8*)(pwi0 + (size_t)(g * 16 + slice) * 1024 + r * 8);
      }
      for (int i = tid; i < 1536; i += 256) {  // wh0: 24 frags -> smem[3072..]
        int g = i >> 9, r = i & 511;
        *(u16x8*)(smem + 3072 + g * 4096 + r * 8) =
            *(const u16x8*)(pwh0 + (size_t)(g * 16 + slice) * 4096 + r * 8);
      }
      __syncthreads();

      f32x4 aR[2], aZ[2], aI[2], aH[2];
#pragma unroll
      for (int f = 0; f < 2; ++f) {
        aR[f] = (f32x4){iR0, iR0, iR0, iR0};
        aZ[f] = (f32x4){iZ0, iZ0, iZ0, iZ0};
        aI[f] = (f32x4){iI0, iI0, iI0, iI0};
        aH[f] = (f32x4){iH0, iH0, iH0, iH0};
      }
      size_t xoff = ((size_t)t * ROWS + arow) * 64 + koff;
      if (f32w)
        gemm_f32A<2>((const float*)x + xoff, 64, smem, lane, aR, aZ, aI);
      else
        gemm_bf16A<2>((const unsigned short*)x + xoff, 64, smem, lane, aR, aZ, aI);
      gemm_bf16A<8>(h0b + (size_t)sp * SLOT + (size_t)arow * HID + koff, HID,
                    smem + 3072, lane, aR, aZ, aH);
#pragma unroll
      for (int f = 0; f < 2; ++f) {
#pragma unroll
        for (int j = 0; j < 4; ++j) {
          int row = rb + f * 16 + rl + j;
          float r = sigm(aR[f][j]);
          float z = sigm(aZ[f][j]);
          float n = tanh_fast(aI[f][j] + r * aH[f][j]);
          float hv = (1.0f - z) * n + z * h0p[f][j];
          h0p[f][j] = hv;
          h0b[(size_t)sc * SLOT + (size_t)row * HID + d] = f2b(hv);
          if (t == 63) stout(out, OUT_HID_OFF + (size_t)row * HID + d, hv, f32w);
        }
      }
      __syncthreads();  // LDS reads done before restage
    }

    // ================= Layer 1, step t-1 =================
    if (t >= 1) {
      const int tm1 = t - 1;
      for (int i = tid; i < 1536; i += 256) {
        int g = i >> 9, r = i & 511;
        *(u16x8*)(smem + g * 4096 + r * 8) =
            *(const u16x8*)(pwi1 + (size_t)(g * 16 + slice) * 4096 + r * 8);
        *(u16x8*)(smem + 12288 + g * 4096 + r * 8) =
            *(const u16x8*)(pwh1 + (size_t)(g * 16 + slice) * 4096 + r * 8);
      }
      __syncthreads();

      f32x4 aR[2], aZ[2], aI[2], aH[2];
#pragma unroll
      for (int f = 0; f < 2; ++f) {
        aR[f] = (f32x4){iR1, iR1, iR1, iR1};
        aZ[f] = (f32x4){iZ1, iZ1, iZ1, iZ1};
        aI[f] = (f32x4){iI1, iI1, iI1, iI1};
        aH[f] = (f32x4){iH1, iH1, iH1, iH1};
      }
      // gi1: A = h0(t-1) (bf16 ring)
      gemm_bf16A<8>(h0b + (size_t)sp * SLOT + (size_t)arow * HID + koff, HID,
                    smem, lane, aR, aZ, aI);
      // gh1: A = h1(t-2) (bf16 ring), skip at tm1==0 (h1(-1)=0)
      if (tm1 >= 1) {
        gemm_bf16A<8>(h1b + (size_t)((tm1 - 1) & 1) * SLOT + (size_t)arow * HID + koff,
                      HID, smem + 12288, lane, aR, aZ, aH);
      }
#pragma unroll
      for (int f = 0; f < 2; ++f) {
#pragma unroll
        for (int j = 0; j < 4; ++j) {
          int row = rb + f * 16 + rl + j;
          float r = sigm(aR[f][j]);
          float z = sigm(aZ[f][j]);
          float n = tanh_fast(aI[f][j] + r * aH[f][j]);
          float hv = (1.0f - z) * n + z * h1p[f][j];
          h1p[f][j] = hv;
          h1b[(size_t)(tm1 & 1) * SLOT + (size_t)row * HID + d] = f2b(hv);
          stout(out, ((size_t)tm1 * ROWS + row) * HID + d, hv, f32w);
          if (tm1 == 63)
            stout(out, OUT_HID_OFF + (size_t)SLOT + (size_t)row * HID + d, hv, f32w);
        }
      }
    }

    if (t < 64) gridbar(cnt, 256u * (unsigned)(t + 1));
  }
}

// --------------------------- host launcher ---------------------------------
extern "C" void kernel_launch(void* const* d_in, const int* in_sizes, int n_in,
                              void* d_out, int out_size, void* d_ws, size_t ws_size,
                              hipStream_t stream) {
  (void)in_sizes; (void)n_in; (void)out_size; (void)ws_size;
  const void* x   = d_in[0];
  const void* wi0 = d_in[1];
  const void* wh0 = d_in[2];
  const void* bi0 = d_in[3];
  const void* bh0 = d_in[4];
  const void* wi1 = d_in[5];
  const void* wh1 = d_in[6];
  const void* bi1 = d_in[7];
  const void* bh1 = d_in[8];
  void* out = d_out;

  char* ws = (char*)d_ws;
  unsigned* cnt  = (unsigned*)ws;                     // 4 B
  unsigned* flag = (unsigned*)(ws + 8);               // 4 B
  unsigned short* h0b = (unsigned short*)(ws + 256);              // 2 MB
  unsigned short* h1b = (unsigned short*)(ws + 256 + 2097152);    // 2 MB
  unsigned short* pwi0 = (unsigned short*)(ws + 256 + 4194304);   // 96 KB
  unsigned short* pwh0 = pwi0 + 49152;                            // 384 KB
  unsigned short* pwi1 = pwh0 + 196608;                           // 384 KB
  unsigned short* pwh1 = pwi1 + 196608;                           // 384 KB

  // zero: cnt + flag + h0b ring (h0(-1) = 0). h1 ring written before read.
  hipMemsetAsync(d_ws, 0, 256 + 2097152, stream);

  probe_dtype<<<1, 64, 0, stream>>>((const unsigned short*)x, flag);

  pack_w<<<(48 * 2 * 64 + 255) / 256, 256, 0, stream>>>(wi0, pwi0, 2, flag);
  pack_w<<<(48 * 8 * 64 + 255) / 256, 256, 0, stream>>>(wh0, pwh0, 8, flag);
  pack_w<<<(48 * 8 * 64 + 255) / 256, 256, 0, stream>>>(wi1, pwi1, 8, flag);
  pack_w<<<(48 * 8 * 64 + 255) / 256, 256, 0, stream>>>(wh1, pwh1, 8, flag);

  void* kargs[] = {&x, &bi0, &bh0, &bi1, &bh1, &pwi0, &pwh0, &pwi1, &pwh1,
                   &out, &h0b, &h1b, &cnt, &flag};
  hipLaunchCooperativeKernel((const void*)gru_main, dim3(256), dim3(256),
                             kargs, 0, stream);
}

// Round 3
// 1282.061 us; speedup vs baseline: 1.6397x; 1.6397x over previous
//
#include <hip/hip_runtime.h>

// ---------------------------------------------------------------------------
// 2-layer GRU, H=256, seq=64, rows = B*N = 2048.
// Rows are independent across the recurrence -> NO global barrier.
// 16 row-groups (128 rows) x 16 dim-slices = 256 WGs; each group of 16 WGs
// synchronizes via its own flag counter (group-local barrier, cross-XCD safe
// via agent-scope release add / acquire fence). group = blockIdx & 15 so
// members sit at stride-16 blockIdx (same XCD under round-robin dispatch).
// Weights staged ONCE into 78 KB persistent dynamic LDS.
// Phase t computes layer0(t) + layer1(t-1); h carried in registers; cross-WG
// h via bf16 rings in ws. Input/output dtype (f32 vs bf16) probed at runtime.
// ---------------------------------------------------------------------------

typedef __attribute__((ext_vector_type(8))) __bf16 bf8;
typedef __attribute__((ext_vector_type(8))) unsigned short u16x8;
typedef __attribute__((ext_vector_type(4))) float f32x4;

#define MFMA16(A, B, C) __builtin_amdgcn_mfma_f32_16x16x32_bf16((A), (B), (C), 0, 0, 0)

#define ROWS 2048
#define HID 256
#define NW 768
#define SLOT (ROWS * HID)                       // 524288
#define OUT_HID_OFF ((size_t)64 * ROWS * HID)   // 33554432

// LDS element offsets (unsigned short units)
#define WI0_OFF 0       // 3072 elems
#define WH0_OFF 3072    // 12288
#define WI1_OFF 15360   // 12288
#define WH1_OFF 27648   // 12288
#define LDS_ELEMS 39936 // 79872 bytes

static __device__ __forceinline__ float b2f(unsigned short u) {
  union { unsigned u32; float f; } v;
  v.u32 = ((unsigned)u) << 16;
  return v.f;
}
static __device__ __forceinline__ unsigned short f2b(float f) {
  unsigned u = __float_as_uint(f);
  u += 0x7fffu + ((u >> 16) & 1u);  // RNE
  return (unsigned short)(u >> 16);
}
static __device__ __forceinline__ float sigm(float x) {
  return 1.0f / (1.0f + __expf(-x));
}
static __device__ __forceinline__ float tanh_fast(float x) {
  x = fminf(15.0f, fmaxf(-15.0f, x));
  float e = __expf(2.0f * x);
  return (e - 1.0f) / (e + 1.0f);
}
static __device__ __forceinline__ float ldin(const void* p, int i, int f32w) {
  return f32w ? ((const float*)p)[i] : b2f(((const unsigned short*)p)[i]);
}
static __device__ __forceinline__ void stout(void* p, size_t i, float v, int f32w) {
  if (f32w) ((float*)p)[i] = v;
  else ((unsigned short*)p)[i] = f2b(v);
}

// --------------------------- dtype probe -----------------------------------
__global__ void probe_dtype(const unsigned short* x, unsigned* flag) {
  if (blockIdx.x != 0 || threadIdx.x != 0) return;
  int cnt = 0;
  for (int i = 0; i < 256; ++i) {
    float v = b2f(x[i]);
    if (v == v && fabsf(v) <= 8.0f) cnt++;
  }
  *flag = (cnt >= 250) ? 0u : 1u;  // 0 = bf16 world, 1 = f32 world
}

// --------------------------- weight pre-pack -------------------------------
// packed[nb][kk][lane][e] = W[kk*32 + (lane>>4)*8 + e][nb*16 + (lane&15)]
__global__ void pack_w(const void* __restrict__ W,
                       unsigned short* __restrict__ P, int KK,
                       const unsigned* __restrict__ flag) {
  int i = blockIdx.x * blockDim.x + threadIdx.x;
  int total = 48 * KK * 64;
  if (i >= total) return;
  int f32w = (int)*flag;
  int l = i & 63;
  int kk = (i >> 6) % KK;
  int nb = i / (64 * KK);
  int n = nb * 16 + (l & 15);
  int k0 = kk * 32 + (l >> 4) * 8;
  u16x8 tmp;
#pragma unroll
  for (int e = 0; e < 8; ++e) tmp[e] = f2b(ldin(W, (k0 + e) * NW + n, f32w));
  *(u16x8*)(P + (size_t)i * 8) = tmp;
}

// --------------------------- GEMM pieces -----------------------------------
template <int KK>
static __device__ __forceinline__ void gemm_bf16A(
    const unsigned short* aBase, int rowStride,
    const unsigned short* smemBase, int lane,
    f32x4* aR, f32x4* aZ, f32x4* aT) {
#pragma unroll
  for (int kk = 0; kk < KK; ++kk) {
    bf8 A0 = *(const bf8*)(aBase + kk * 32);
    bf8 A1 = *(const bf8*)(aBase + 16 * rowStride + kk * 32);
    bf8 Br = *(const bf8*)(smemBase + (0 * KK + kk) * 512 + lane * 8);
    bf8 Bz = *(const bf8*)(smemBase + (1 * KK + kk) * 512 + lane * 8);
    bf8 Bn = *(const bf8*)(smemBase + (2 * KK + kk) * 512 + lane * 8);
    aR[0] = MFMA16(A0, Br, aR[0]);
    aR[1] = MFMA16(A1, Br, aR[1]);
    aZ[0] = MFMA16(A0, Bz, aZ[0]);
    aZ[1] = MFMA16(A1, Bz, aZ[1]);
    aT[0] = MFMA16(A0, Bn, aT[0]);
    aT[1] = MFMA16(A1, Bn, aT[1]);
  }
}

template <int KK>
static __device__ __forceinline__ void gemm_f32A(
    const float* aBase, int rowStride,
    const unsigned short* smemBase, int lane,
    f32x4* aR, f32x4* aZ, f32x4* aT) {
#pragma unroll
  for (int kk = 0; kk < KK; ++kk) {
    union { u16x8 u; bf8 b; } A0, A1;
#pragma unroll
    for (int e = 0; e < 8; ++e) {
      A0.u[e] = f2b(aBase[kk * 32 + e]);
      A1.u[e] = f2b(aBase[16 * rowStride + kk * 32 + e]);
    }
    bf8 Br = *(const bf8*)(smemBase + (0 * KK + kk) * 512 + lane * 8);
    bf8 Bz = *(const bf8*)(smemBase + (1 * KK + kk) * 512 + lane * 8);
    bf8 Bn = *(const bf8*)(smemBase + (2 * KK + kk) * 512 + lane * 8);
    aR[0] = MFMA16(A0.b, Br, aR[0]);
    aR[1] = MFMA16(A1.b, Br, aR[1]);
    aZ[0] = MFMA16(A0.b, Bz, aZ[0]);
    aZ[1] = MFMA16(A1.b, Bz, aZ[1]);
    aT[0] = MFMA16(A0.b, Bn, aT[0]);
    aT[1] = MFMA16(A1.b, Bn, aT[1]);
  }
}

// --------------------------- main kernel -----------------------------------
__global__ void __launch_bounds__(256, 1) gru_main(
    const void* __restrict__ x,
    const void* __restrict__ bi0, const void* __restrict__ bh0,
    const void* __restrict__ bi1, const void* __restrict__ bh1,
    const unsigned short* __restrict__ pwi0, const unsigned short* __restrict__ pwh0,
    const unsigned short* __restrict__ pwi1, const unsigned short* __restrict__ pwh1,
    void* __restrict__ out,
    unsigned short* __restrict__ h0b, unsigned short* __restrict__ h1b,
    unsigned* __restrict__ flags, const unsigned* __restrict__ flag) {
  extern __shared__ __align__(16) unsigned short smem[];  // 79872 B

  const int f32w = (int)*flag;
  const int tid = threadIdx.x;
  const int lane = tid & 63;
  const int wid = tid >> 6;
  const int bid = blockIdx.x;
  const int g = bid & 15;       // row group (128 rows) — stride-16 blockIdx
  const int slice = bid >> 4;   // dim slice (16 hidden dims)

  const int d = slice * 16 + (lane & 15);
  const int rb = g * 128 + wid * 32;
  const int arow = rb + (lane & 15);
  const int koff = (lane >> 4) * 8;
  const int rl = (lane >> 4) * 4;

  unsigned* flagp = flags + (size_t)g * 64;  // 256 B stride per group

  // ---- stage all weights for this slice into LDS (once) ----
  for (int i = tid; i < 384; i += 256) {  // wi0: 6 frags
    int gg = i >> 7, r = i & 127;
    *(u16x8*)(smem + WI0_OFF + gg * 1024 + r * 8) =
        *(const u16x8*)(pwi0 + (size_t)(gg * 16 + slice) * 1024 + r * 8);
  }
  for (int i = tid; i < 1536; i += 256) {  // wh0 / wi1 / wh1: 24 frags each
    int gg = i >> 9, r = i & 511;
    *(u16x8*)(smem + WH0_OFF + gg * 4096 + r * 8) =
        *(const u16x8*)(pwh0 + (size_t)(gg * 16 + slice) * 4096 + r * 8);
    *(u16x8*)(smem + WI1_OFF + gg * 4096 + r * 8) =
        *(const u16x8*)(pwi1 + (size_t)(gg * 16 + slice) * 4096 + r * 8);
    *(u16x8*)(smem + WH1_OFF + gg * 4096 + r * 8) =
        *(const u16x8*)(pwh1 + (size_t)(gg * 16 + slice) * 4096 + r * 8);
  }
  __syncthreads();

  const float iR0 = ldin(bi0, d, f32w) + ldin(bh0, d, f32w);
  const float iZ0 = ldin(bi0, 256 + d, f32w) + ldin(bh0, 256 + d, f32w);
  const float iI0 = ldin(bi0, 512 + d, f32w);
  const float iH0 = ldin(bh0, 512 + d, f32w);
  const float iR1 = ldin(bi1, d, f32w) + ldin(bh1, d, f32w);
  const float iZ1 = ldin(bi1, 256 + d, f32w) + ldin(bh1, 256 + d, f32w);
  const float iI1 = ldin(bi1, 512 + d, f32w);
  const float iH1 = ldin(bh1, 512 + d, f32w);

  float h0p[2][4] = {{0, 0, 0, 0}, {0, 0, 0, 0}};
  float h1p[2][4] = {{0, 0, 0, 0}, {0, 0, 0, 0}};

  for (int t = 0; t <= 64; ++t) {
    const int sc = t & 1;
    const int sp = sc ^ 1;

    // ---- group-local barrier: wait for all 16 WGs' phase-(t-1) arrivals ----
    if (t > 0) {
      if (tid == 0) {
        const unsigned tgt = 16u * (unsigned)t;
        unsigned v = __hip_atomic_load(flagp, __ATOMIC_RELAXED, __HIP_MEMORY_SCOPE_AGENT);
        while (v < tgt) {
          __builtin_amdgcn_s_sleep(2);
          v = __hip_atomic_load(flagp, __ATOMIC_RELAXED, __HIP_MEMORY_SCOPE_AGENT);
        }
        __threadfence();  // acquire: invalidate stale L1/L2 (covers whole CU/XCD)
      }
      __syncthreads();
    }

    // ================= Layer 0, step t =================
    if (t < 64) {
      f32x4 aR[2], aZ[2], aI[2], aH[2];
#pragma unroll
      for (int f = 0; f < 2; ++f) {
        aR[f] = (f32x4){iR0, iR0, iR0, iR0};
        aZ[f] = (f32x4){iZ0, iZ0, iZ0, iZ0};
        aI[f] = (f32x4){iI0, iI0, iI0, iI0};
        aH[f] = (f32x4){iH0, iH0, iH0, iH0};
      }
      size_t xoff = ((size_t)t * ROWS + arow) * 64 + koff;
      if (f32w)
        gemm_f32A<2>((const float*)x + xoff, 64, smem + WI0_OFF, lane, aR, aZ, aI);
      else
        gemm_bf16A<2>((const unsigned short*)x + xoff, 64, smem + WI0_OFF, lane, aR, aZ, aI);
      gemm_bf16A<8>(h0b + (size_t)sp * SLOT + (size_t)arow * HID + koff, HID,
                    smem + WH0_OFF, lane, aR, aZ, aH);
#pragma unroll
      for (int f = 0; f < 2; ++f) {
#pragma unroll
        for (int j = 0; j < 4; ++j) {
          int row = rb + f * 16 + rl + j;
          float r = sigm(aR[f][j]);
          float z = sigm(aZ[f][j]);
          float n = tanh_fast(aI[f][j] + r * aH[f][j]);
          float hv = (1.0f - z) * n + z * h0p[f][j];
          h0p[f][j] = hv;
          h0b[(size_t)sc * SLOT + (size_t)row * HID + d] = f2b(hv);
          if (t == 63) stout(out, OUT_HID_OFF + (size_t)row * HID + d, hv, f32w);
        }
      }
    }

    // ================= Layer 1, step t-1 =================
    if (t >= 1) {
      const int tm1 = t - 1;
      f32x4 aR[2], aZ[2], aI[2], aH[2];
#pragma unroll
      for (int f = 0; f < 2; ++f) {
        aR[f] = (f32x4){iR1, iR1, iR1, iR1};
        aZ[f] = (f32x4){iZ1, iZ1, iZ1, iZ1};
        aI[f] = (f32x4){iI1, iI1, iI1, iI1};
        aH[f] = (f32x4){iH1, iH1, iH1, iH1};
      }
      gemm_bf16A<8>(h0b + (size_t)sp * SLOT + (size_t)arow * HID + koff, HID,
                    smem + WI1_OFF, lane, aR, aZ, aI);
      if (tm1 >= 1) {
        gemm_bf16A<8>(h1b + (size_t)((tm1 - 1) & 1) * SLOT + (size_t)arow * HID + koff,
                      HID, smem + WH1_OFF, lane, aR, aZ, aH);
      }
#pragma unroll
      for (int f = 0; f < 2; ++f) {
#pragma unroll
        for (int j = 0; j < 4; ++j) {
          int row = rb + f * 16 + rl + j;
          float r = sigm(aR[f][j]);
          float z = sigm(aZ[f][j]);
          float n = tanh_fast(aI[f][j] + r * aH[f][j]);
          float hv = (1.0f - z) * n + z * h1p[f][j];
          h1p[f][j] = hv;
          h1b[(size_t)(tm1 & 1) * SLOT + (size_t)row * HID + d] = f2b(hv);
          stout(out, ((size_t)tm1 * ROWS + row) * HID + d, hv, f32w);
          if (tm1 == 63)
            stout(out, OUT_HID_OFF + (size_t)SLOT + (size_t)row * HID + d, hv, f32w);
        }
      }
    }

    // ---- arrival: syncthreads drains all waves' stores (vmcnt0), then one
    // release-add per WG (wbl2 flushes the XCD L2 incl. all waves' h lines) ----
    __syncthreads();
    if (tid == 0)
      __hip_atomic_fetch_add(flagp, 1u, __ATOMIC_RELEASE, __HIP_MEMORY_SCOPE_AGENT);
  }
}

// --------------------------- host launcher ---------------------------------
extern "C" void kernel_launch(void* const* d_in, const int* in_sizes, int n_in,
                              void* d_out, int out_size, void* d_ws, size_t ws_size,
                              hipStream_t stream) {
  (void)in_sizes; (void)n_in; (void)out_size; (void)ws_size;
  const void* x   = d_in[0];
  const void* wi0 = d_in[1];
  const void* wh0 = d_in[2];
  const void* bi0 = d_in[3];
  const void* bh0 = d_in[4];
  const void* wi1 = d_in[5];
  const void* wh1 = d_in[6];
  const void* bi1 = d_in[7];
  const void* bh1 = d_in[8];
  void* out = d_out;

  char* ws = (char*)d_ws;
  unsigned* flags = (unsigned*)ws;                                 // 16 x 256 B
  unsigned* flag  = (unsigned*)(ws + 4080);                        // dtype flag
  unsigned short* h0b = (unsigned short*)(ws + 4096);              // 2 MB
  unsigned short* h1b = (unsigned short*)(ws + 4096 + 2097152);    // 2 MB
  unsigned short* pwi0 = (unsigned short*)(ws + 4096 + 4194304);   // 96 KB
  unsigned short* pwh0 = pwi0 + 49152;                             // 384 KB
  unsigned short* pwi1 = pwh0 + 196608;                            // 384 KB
  unsigned short* pwh1 = pwi1 + 196608;                            // 384 KB

  // zero: flags + dtype flag + h0b ring (h0(-1) = 0). h1b written before read.
  hipMemsetAsync(d_ws, 0, 4096 + 2097152, stream);

  probe_dtype<<<1, 64, 0, stream>>>((const unsigned short*)x, flag);

  pack_w<<<(48 * 2 * 64 + 255) / 256, 256, 0, stream>>>(wi0, pwi0, 2, flag);
  pack_w<<<(48 * 8 * 64 + 255) / 256, 256, 0, stream>>>(wh0, pwh0, 8, flag);
  pack_w<<<(48 * 8 * 64 + 255) / 256, 256, 0, stream>>>(wi1, pwi1, 8, flag);
  pack_w<<<(48 * 8 * 64 + 255) / 256, 256, 0, stream>>>(wh1, pwh1, 8, flag);

  hipFuncSetAttribute((const void*)gru_main,
                      hipFuncAttributeMaxDynamicSharedMemorySize,
                      LDS_ELEMS * 2);

  void* kargs[] = {&x, &bi0, &bh0, &bi1, &bh1, &pwi0, &pwh0, &pwi1, &pwh1,
                   &out, &h0b, &h1b, &flags, &flag};
  hipLaunchCooperativeKernel((const void*)gru_main, dim3(256), dim3(256),
                             kargs, LDS_ELEMS * 2, stream);
}

// Round 6
// 793.315 us; speedup vs baseline: 2.6499x; 1.6161x over previous
//
#include <hip/hip_runtime.h>

// ---------------------------------------------------------------------------
// 2-layer GRU, H=256, seq=64, rows = B*N = 2048.
// 16 row-groups (128 rows) x 16 dim-slices = 256 WGs, grid 256 (1/CU).
// Fence-free sync: h rings written with MALL-coherent stores
// (global_store_short sc0 sc1) and read with agent-scope relaxed u64 atomic
// loads -> correct under any WG->XCD placement, no wbl2/inv anywhere.
// Group barrier: explicit vmcnt(0) drain + __syncthreads + one relaxed flag
// add; waiters poll relaxed. g = bid & 15 keeps group members on one XCD
// under round-robin dispatch (perf heuristic only).
// Fused h0 GEMM: h0(t-1) A-frags feed wh0 (layer0) AND wi1 (layer1).
// LDS: STATIC 48 KB (wi1 + wh1). wh0/wi0 B-frags read from global (L2-hot).
// Launch: cooperative, with CHECKED error + plain-launch fallback (sync is
// group-local, so a plain launch at 1 WG/CU is equally correct).
// ---------------------------------------------------------------------------

typedef __attribute__((ext_vector_type(8))) __bf16 bf8;
typedef __attribute__((ext_vector_type(8))) unsigned short u16x8;
typedef __attribute__((ext_vector_type(4))) float f32x4;

#define MFMA16(A, B, C) __builtin_amdgcn_mfma_f32_16x16x32_bf16((A), (B), (C), 0, 0, 0)

#define ROWS 2048
#define HID 256
#define NW 768
#define SLOT (ROWS * HID)                       // 524288
#define OUT_HID_OFF ((size_t)64 * ROWS * HID)   // 33554432

// Static LDS layout (u16 units): wi1 @0, wh1 @12288. 24576 elems = 48 KB.
#define WI1_OFF 0
#define WH1_OFF 12288

static __device__ __forceinline__ float b2f(unsigned short u) {
  union { unsigned u32; float f; } v;
  v.u32 = ((unsigned)u) << 16;
  return v.f;
}
static __device__ __forceinline__ unsigned short f2b(float f) {
  unsigned u = __float_as_uint(f);
  u += 0x7fffu + ((u >> 16) & 1u);  // RNE
  return (unsigned short)(u >> 16);
}
static __device__ __forceinline__ float sigm(float x) {
  return 1.0f / (1.0f + __expf(-x));
}
static __device__ __forceinline__ float tanh_fast(float x) {
  x = fminf(15.0f, fmaxf(-15.0f, x));
  float e = __expf(2.0f * x);
  return (e - 1.0f) / (e + 1.0f);
}
static __device__ __forceinline__ float ldin(const void* p, int i, int f32w) {
  return f32w ? ((const float*)p)[i] : b2f(((const unsigned short*)p)[i]);
}
static __device__ __forceinline__ void stout(void* p, size_t i, float v, int f32w) {
  if (f32w) ((float*)p)[i] = v;
  else ((unsigned short*)p)[i] = f2b(v);
}

// Coherent 16B load as MFMA A-fragment: two relaxed agent-scope u64 atomic
// loads (sc bits bypass stale L1/L2; served at the MALL coherence point).
static __device__ __forceinline__ bf8 ld_h16(const unsigned short* p) {
  union { unsigned long long q[2]; bf8 b; } u;
  u.q[0] = __hip_atomic_load((const unsigned long long*)p, __ATOMIC_RELAXED,
                             __HIP_MEMORY_SCOPE_AGENT);
  u.q[1] = __hip_atomic_load((const unsigned long long*)(p + 4), __ATOMIC_RELAXED,
                             __HIP_MEMORY_SCOPE_AGENT);
  return u.b;
}
// Coherent 2B store (MALL write-through). Counted by vmcnt; we drain with an
// explicit s_waitcnt before the arrival barrier.
static __device__ __forceinline__ void st_h2(unsigned short* p, unsigned short v) {
  asm volatile("global_store_short %0, %1, off sc0 sc1"
               : : "v"(p), "v"((unsigned)v) : "memory");
}

// --------------------------- dtype probe -----------------------------------
__global__ void probe_dtype(const unsigned short* x, unsigned* flag) {
  if (blockIdx.x != 0 || threadIdx.x != 0) return;
  int cnt = 0;
  for (int i = 0; i < 256; ++i) {
    float v = b2f(x[i]);
    if (v == v && fabsf(v) <= 8.0f) cnt++;
  }
  *flag = (cnt >= 250) ? 0u : 1u;  // 0 = bf16 world, 1 = f32 world
}

// --------------------------- weight pre-pack -------------------------------
// packed[nb][kk][lane][e] = W[kk*32 + (lane>>4)*8 + e][nb*16 + (lane&15)]
__global__ void pack_w(const void* __restrict__ W,
                       unsigned short* __restrict__ P, int KK,
                       const unsigned* __restrict__ flag) {
  int i = blockIdx.x * blockDim.x + threadIdx.x;
  int total = 48 * KK * 64;
  if (i >= total) return;
  int f32w = (int)*flag;
  int l = i & 63;
  int kk = (i >> 6) % KK;
  int nb = i / (64 * KK);
  int n = nb * 16 + (l & 15);
  int k0 = kk * 32 + (l >> 4) * 8;
  u16x8 tmp;
#pragma unroll
  for (int e = 0; e < 8; ++e) tmp[e] = f2b(ldin(W, (k0 + e) * NW + n, f32w));
  *(u16x8*)(P + (size_t)i * 8) = tmp;
}

// --------------------------- GEMM pieces -----------------------------------
// x-GEMM (K=64): A plain-cached (read-only input), B frags from global (L2).
static __device__ __forceinline__ void gemm_x_bf16(
    const unsigned short* aBase, const unsigned short* xw, int lane,
    f32x4* aR, f32x4* aZ, f32x4* aT) {
#pragma unroll
  for (int kk = 0; kk < 2; ++kk) {
    bf8 A0 = *(const bf8*)(aBase + kk * 32);
    bf8 A1 = *(const bf8*)(aBase + 16 * 64 + kk * 32);
    const int lb = lane * 8;
    bf8 Br = *(const bf8*)(xw + 0 * 16384 + kk * 512 + lb);
    bf8 Bz = *(const bf8*)(xw + 1 * 16384 + kk * 512 + lb);
    bf8 Bn = *(const bf8*)(xw + 2 * 16384 + kk * 512 + lb);
    aR[0] = MFMA16(A0, Br, aR[0]);
    aR[1] = MFMA16(A1, Br, aR[1]);
    aZ[0] = MFMA16(A0, Bz, aZ[0]);
    aZ[1] = MFMA16(A1, Bz, aZ[1]);
    aT[0] = MFMA16(A0, Bn, aT[0]);
    aT[1] = MFMA16(A1, Bn, aT[1]);
  }
}
static __device__ __forceinline__ void gemm_x_f32(
    const float* aBase, const unsigned short* xw, int lane,
    f32x4* aR, f32x4* aZ, f32x4* aT) {
#pragma unroll
  for (int kk = 0; kk < 2; ++kk) {
    union { u16x8 u; bf8 b; } A0, A1;
#pragma unroll
    for (int e = 0; e < 8; ++e) {
      A0.u[e] = f2b(aBase[kk * 32 + e]);
      A1.u[e] = f2b(aBase[16 * 64 + kk * 32 + e]);
    }
    const int lb = lane * 8;
    bf8 Br = *(const bf8*)(xw + 0 * 16384 + kk * 512 + lb);
    bf8 Bz = *(const bf8*)(xw + 1 * 16384 + kk * 512 + lb);
    bf8 Bn = *(const bf8*)(xw + 2 * 16384 + kk * 512 + lb);
    aR[0] = MFMA16(A0.b, Br, aR[0]);
    aR[1] = MFMA16(A1.b, Br, aR[1]);
    aZ[0] = MFMA16(A0.b, Bz, aZ[0]);
    aZ[1] = MFMA16(A1.b, Bz, aZ[1]);
    aT[0] = MFMA16(A0.b, Bn, aT[0]);
    aT[1] = MFMA16(A1.b, Bn, aT[1]);
  }
}
// Fused h0 GEMM: coherent h0(t-1) A-frags feed wh0 (global, layer0) AND
// wi1 (LDS, layer1).
static __device__ __forceinline__ void gemm_h0(
    const unsigned short* aBase, const unsigned short* w0,
    const unsigned short* smem, int lane,
    f32x4* aR0, f32x4* aZ0, f32x4* aH0,
    f32x4* aR1, f32x4* aZ1, f32x4* aI1) {
#pragma unroll
  for (int kk = 0; kk < 8; ++kk) {
    bf8 A0 = ld_h16(aBase + kk * 32);
    bf8 A1 = ld_h16(aBase + 16 * HID + kk * 32);
    const int lb = lane * 8;
    bf8 Br0 = *(const bf8*)(w0 + 0 * 65536 + kk * 512 + lb);
    bf8 Bz0 = *(const bf8*)(w0 + 1 * 65536 + kk * 512 + lb);
    bf8 Bn0 = *(const bf8*)(w0 + 2 * 65536 + kk * 512 + lb);
    bf8 Br1 = *(const bf8*)(smem + WI1_OFF + (0 * 8 + kk) * 512 + lb);
    bf8 Bz1 = *(const bf8*)(smem + WI1_OFF + (1 * 8 + kk) * 512 + lb);
    bf8 Bn1 = *(const bf8*)(smem + WI1_OFF + (2 * 8 + kk) * 512 + lb);
    aR0[0] = MFMA16(A0, Br0, aR0[0]);
    aR0[1] = MFMA16(A1, Br0, aR0[1]);
    aZ0[0] = MFMA16(A0, Bz0, aZ0[0]);
    aZ0[1] = MFMA16(A1, Bz0, aZ0[1]);
    aH0[0] = MFMA16(A0, Bn0, aH0[0]);
    aH0[1] = MFMA16(A1, Bn0, aH0[1]);
    aR1[0] = MFMA16(A0, Br1, aR1[0]);
    aR1[1] = MFMA16(A1, Br1, aR1[1]);
    aZ1[0] = MFMA16(A0, Bz1, aZ1[0]);
    aZ1[1] = MFMA16(A1, Bz1, aZ1[1]);
    aI1[0] = MFMA16(A0, Bn1, aI1[0]);
    aI1[1] = MFMA16(A1, Bn1, aI1[1]);
  }
}
static __device__ __forceinline__ void gemm_h1(
    const unsigned short* aBase, const unsigned short* smem, int lane,
    f32x4* aR, f32x4* aZ, f32x4* aH) {
#pragma unroll
  for (int kk = 0; kk < 8; ++kk) {
    bf8 A0 = ld_h16(aBase + kk * 32);
    bf8 A1 = ld_h16(aBase + 16 * HID + kk * 32);
    const int lb = lane * 8;
    bf8 Br = *(const bf8*)(smem + WH1_OFF + (0 * 8 + kk) * 512 + lb);
    bf8 Bz = *(const bf8*)(smem + WH1_OFF + (1 * 8 + kk) * 512 + lb);
    bf8 Bn = *(const bf8*)(smem + WH1_OFF + (2 * 8 + kk) * 512 + lb);
    aR[0] = MFMA16(A0, Br, aR[0]);
    aR[1] = MFMA16(A1, Br, aR[1]);
    aZ[0] = MFMA16(A0, Bz, aZ[0]);
    aZ[1] = MFMA16(A1, Bz, aZ[1]);
    aH[0] = MFMA16(A0, Bn, aH[0]);
    aH[1] = MFMA16(A1, Bn, aH[1]);
  }
}

// --------------------------- main kernel -----------------------------------
__global__ void __launch_bounds__(256, 1) gru_main(
    const void* __restrict__ x,
    const void* __restrict__ bi0, const void* __restrict__ bh0,
    const void* __restrict__ bi1, const void* __restrict__ bh1,
    const unsigned short* __restrict__ pwi0, const unsigned short* __restrict__ pwh0,
    const unsigned short* __restrict__ pwi1, const unsigned short* __restrict__ pwh1,
    void* __restrict__ out,
    unsigned short* __restrict__ h0b, unsigned short* __restrict__ h1b,
    unsigned* __restrict__ flags, const unsigned* __restrict__ flag) {
  __shared__ __align__(16) unsigned short smem[24576];  // 48 KB static

  const int f32w = (int)*flag;
  const int tid = threadIdx.x;
  const int lane = tid & 63;
  const int wid = tid >> 6;
  const int bid = blockIdx.x;
  const int g = bid & 15;      // row group (128 rows) — members share an XCD
  const int slice = bid >> 4;  // dim slice (16 hidden dims)

  const int d = slice * 16 + (lane & 15);
  const int rb = g * 128 + wid * 32;
  const int arow = rb + (lane & 15);
  const int koff = (lane >> 4) * 8;
  const int rl = (lane >> 4) * 4;

  unsigned* flagp = flags + (size_t)g * 64;  // 256 B stride per group

  // ---- stage wi1 / wh1 for this slice into static LDS (once) ----
  for (int i = tid; i < 1536; i += 256) {
    int gg = i >> 9, r = i & 511;
    *(u16x8*)(smem + WI1_OFF + gg * 4096 + r * 8) =
        *(const u16x8*)(pwi1 + (size_t)(gg * 16 + slice) * 4096 + r * 8);
    *(u16x8*)(smem + WH1_OFF + gg * 4096 + r * 8) =
        *(const u16x8*)(pwh1 + (size_t)(gg * 16 + slice) * 4096 + r * 8);
  }
  __syncthreads();

  const unsigned short* xw = pwi0 + (size_t)slice * 1024;  // wi0 frag base
  const unsigned short* w0 = pwh0 + (size_t)slice * 4096;  // wh0 frag base

  const float iR0 = ldin(bi0, d, f32w) + ldin(bh0, d, f32w);
  const float iZ0 = ldin(bi0, 256 + d, f32w) + ldin(bh0, 256 + d, f32w);
  const float iI0 = ldin(bi0, 512 + d, f32w);
  const float iH0 = ldin(bh0, 512 + d, f32w);
  const float iR1 = ldin(bi1, d, f32w) + ldin(bh1, d, f32w);
  const float iZ1 = ldin(bi1, 256 + d, f32w) + ldin(bh1, 256 + d, f32w);
  const float iI1 = ldin(bi1, 512 + d, f32w);
  const float iH1 = ldin(bh1, 512 + d, f32w);

  float h0p[2][4] = {{0, 0, 0, 0}, {0, 0, 0, 0}};
  float h1p[2][4] = {{0, 0, 0, 0}, {0, 0, 0, 0}};

  for (int t = 0; t <= 64; ++t) {
    const int sc = t & 1;
    const int sp = sc ^ 1;

    f32x4 aR0[2], aZ0[2], aI0[2], aH0[2], aR1[2], aZ1[2], aI1[2], aH1[2];
#pragma unroll
    for (int f = 0; f < 2; ++f) {
      aR0[f] = (f32x4){iR0, iR0, iR0, iR0};
      aZ0[f] = (f32x4){iZ0, iZ0, iZ0, iZ0};
      aI0[f] = (f32x4){iI0, iI0, iI0, iI0};
      aH0[f] = (f32x4){iH0, iH0, iH0, iH0};
      aR1[f] = (f32x4){iR1, iR1, iR1, iR1};
      aZ1[f] = (f32x4){iZ1, iZ1, iZ1, iZ1};
      aI1[f] = (f32x4){iI1, iI1, iI1, iI1};
      aH1[f] = (f32x4){iH1, iH1, iH1, iH1};
    }

    // ---- x-GEMM prefetch (no group dependency) ----
    if (t < 64) {
      size_t xoff = ((size_t)t * ROWS + arow) * 64 + koff;
      if (f32w) gemm_x_f32((const float*)x + xoff, xw, lane, aR0, aZ0, aI0);
      else gemm_x_bf16((const unsigned short*)x + xoff, xw, lane, aR0, aZ0, aI0);
    }

    // ---- group barrier wait: all 16 WGs finished phase t-1 ----
    if (t > 0) {
      if (tid == 0) {
        const unsigned tgt = 16u * (unsigned)t;
        while (__hip_atomic_load(flagp, __ATOMIC_RELAXED,
                                 __HIP_MEMORY_SCOPE_AGENT) < tgt)
          __builtin_amdgcn_s_sleep(1);
      }
      __syncthreads();
    }

    // ---- fused h0(t-1) GEMM: layer0 gates + layer1 gi ----
    gemm_h0(h0b + (size_t)sp * SLOT + (size_t)arow * HID + koff, w0, smem,
            lane, aR0, aZ0, aH0, aR1, aZ1, aI1);
    // ---- h1(t-2) GEMM: layer1 gh (h1(-1)=0 -> skip for t<2) ----
    if (t >= 2)
      gemm_h1(h1b + (size_t)sc * SLOT + (size_t)arow * HID + koff, smem, lane,
              aR1, aZ1, aH1);

    // ---- layer0 epilogue: h0(t) ----
    if (t < 64) {
#pragma unroll
      for (int f = 0; f < 2; ++f) {
#pragma unroll
        for (int j = 0; j < 4; ++j) {
          int row = rb + f * 16 + rl + j;
          float r = sigm(aR0[f][j]);
          float z = sigm(aZ0[f][j]);
          float n = tanh_fast(aI0[f][j] + r * aH0[f][j]);
          float hv = (1.0f - z) * n + z * h0p[f][j];
          h0p[f][j] = hv;
          st_h2(h0b + (size_t)sc * SLOT + (size_t)row * HID + d, f2b(hv));
          if (t == 63) stout(out, OUT_HID_OFF + (size_t)row * HID + d, hv, f32w);
        }
      }
    }
    // ---- layer1 epilogue: h1(t-1) ----
    if (t >= 1) {
      const int tm1 = t - 1;
#pragma unroll
      for (int f = 0; f < 2; ++f) {
#pragma unroll
        for (int j = 0; j < 4; ++j) {
          int row = rb + f * 16 + rl + j;
          float r = sigm(aR1[f][j]);
          float z = sigm(aZ1[f][j]);
          float n = tanh_fast(aI1[f][j] + r * aH1[f][j]);
          float hv = (1.0f - z) * n + z * h1p[f][j];
          h1p[f][j] = hv;
          st_h2(h1b + (size_t)sp * SLOT + (size_t)row * HID + d, f2b(hv));
          stout(out, ((size_t)tm1 * ROWS + row) * HID + d, hv, f32w);
          if (tm1 == 63)
            stout(out, OUT_HID_OFF + (size_t)SLOT + (size_t)row * HID + d, hv, f32w);
        }
      }
    }

    // ---- arrival: drain ALL vmem (incl. inline-asm ring stores) before the
    // barrier, then one relaxed flag add (data already at coherence point) ----
    asm volatile("s_waitcnt vmcnt(0)" ::: "memory");
    __syncthreads();
    if (t < 64 && tid == 0)
      __hip_atomic_fetch_add(flagp, 1u, __ATOMIC_RELAXED, __HIP_MEMORY_SCOPE_AGENT);
  }
}

// --------------------------- host launcher ---------------------------------
extern "C" void kernel_launch(void* const* d_in, const int* in_sizes, int n_in,
                              void* d_out, int out_size, void* d_ws, size_t ws_size,
                              hipStream_t stream) {
  (void)in_sizes; (void)n_in; (void)out_size; (void)ws_size;
  const void* x   = d_in[0];
  const void* wi0 = d_in[1];
  const void* wh0 = d_in[2];
  const void* bi0 = d_in[3];
  const void* bh0 = d_in[4];
  const void* wi1 = d_in[5];
  const void* wh1 = d_in[6];
  const void* bi1 = d_in[7];
  const void* bh1 = d_in[8];
  void* out = d_out;

  char* ws = (char*)d_ws;
  unsigned* flags = (unsigned*)ws;                                // 16 x 256 B
  unsigned* flag  = (unsigned*)(ws + 4096);                       // dtype flag
  unsigned short* h0b = (unsigned short*)(ws + 8192);             // 2 MB
  unsigned short* h1b = (unsigned short*)(ws + 8192 + 2097152);   // 2 MB
  unsigned short* pwi0 = (unsigned short*)(ws + 8192 + 4194304);  // 96 KB
  unsigned short* pwh0 = pwi0 + 49152;                            // 384 KB
  unsigned short* pwi1 = pwh0 + 196608;                           // 384 KB
  unsigned short* pwh1 = pwi1 + 196608;                           // 384 KB

  // zero: flags + dtype flag + h0b ring (h0(-1)=0). h1b written before read.
  hipMemsetAsync(d_ws, 0, 8192 + 2097152, stream);

  probe_dtype<<<1, 64, 0, stream>>>((const unsigned short*)x, flag);

  pack_w<<<(48 * 2 * 64 + 255) / 256, 256, 0, stream>>>(wi0, pwi0, 2, flag);
  pack_w<<<(48 * 8 * 64 + 255) / 256, 256, 0, stream>>>(wh0, pwh0, 8, flag);
  pack_w<<<(48 * 8 * 64 + 255) / 256, 256, 0, stream>>>(wi1, pwi1, 8, flag);
  pack_w<<<(48 * 8 * 64 + 255) / 256, 256, 0, stream>>>(wh1, pwh1, 8, flag);

  void* kargs[] = {&x, &bi0, &bh0, &bi1, &bh1, &pwi0, &pwh0, &pwi1, &pwh1,
                   &out, &h0b, &h1b, &flags, &flag};
  hipError_t lerr = hipLaunchCooperativeKernel(
      (const void*)gru_main, dim3(256), dim3(256), kargs, 0, stream);
  if (lerr != hipSuccess) {
    (void)hipGetLastError();  // clear sticky error; fall back to plain launch
    gru_main<<<dim3(256), dim3(256), 0, stream>>>(
        x, bi0, bh0, bi1, bh1, pwi0, pwh0, pwi1, pwh1,
        out, h0b, h1b, flags, flag);
  }
}